// Round 8
// baseline (352.095 us; speedup 1.0000x reference)
//
#include <hip/hip_runtime.h>

// loss = a*sum(pn^2) + 2*sum(z)*sum(pn) + sum(z^2)*(N - a)
//   z = (margin - p) on positives, pn = p on negatives, a = #positives.
// Streaming reduction: 268 MB read, one scalar out.
//
// R12 (final ledger): L3 schemes are closed — R7 lockstep 3.4 TB/s, R10
// partition worse, R11 phase-split measured L3 load-service at only ~2.8
// TB/s (slower than nt-HBM!). Pure-nt streaming (R8) = 4.1 TB/s read is the
// best and exceeds all documented read references (m13 copy read ~3.15,
// m146 4.89 total). MLP null (R9), occupancy null (R6) -> ~4.1 TB/s is the
// read roofline for this shape. This version: exact R8 memory structure +
// fuse the final kernel via last-block-completes (4-byte counter memset,
// threadfence release/acquire) -> one fewer dispatch + gap.
// Predict: reduce ~65-68 us unchanged, FETCH ~262 MB, total ~240-245 us.
// Remaining floor: 2x 512 MiB harness poison fills (~158 us) + read time.

constexpr float MARGIN = 1.0f;

#define BLOCK 256
#define MAX_BLOCKS 2048
#define SLOT_STRIDE 8            // floats per block slot (32 B)

typedef float v4f __attribute__((ext_vector_type(4)));
typedef int   v4i __attribute__((ext_vector_type(4)));

__device__ __forceinline__ float wave_reduce(float v) {
    #pragma unroll
    for (int off = 32; off > 0; off >>= 1) v += __shfl_down(v, off, 64);
    return v;
}

struct Acc { float a, sz, sz2, sp, sp2; };

__device__ __forceinline__ void acc1(float px, int lx, Acc& s) {
    float ispos = (lx == 1) ? 1.0f : 0.0f;
    float z  = ispos * (MARGIN - px);
    s.a   += ispos;
    s.sz  += z;
    s.sz2  = fmaf(z, z, s.sz2);
    float pn = (lx == 1) ? 0.0f : px;
    s.sp  += pn;
    s.sp2  = fmaf(pn, pn, s.sp2);
}

__device__ __forceinline__ void acc4(const v4f& p, const v4i& l, Acc& s) {
    acc1(p[0], l[0], s);
    acc1(p[1], l[1], s);
    acc1(p[2], l[2], s);
    acc1(p[3], l[3], s);
}

__global__ __launch_bounds__(BLOCK, 8) void hinge2_fused(
    const float* __restrict__ pred, const int* __restrict__ lab,
    float* __restrict__ ws, unsigned* __restrict__ cnt,
    float* __restrict__ out, int n, int nvec, int tail_start)
{
    const v4f* p4 = reinterpret_cast<const v4f*>(pred);
    const v4i* l4 = reinterpret_cast<const v4i*>(lab);

    Acc s = {0.f, 0.f, 0.f, 0.f, 0.f};
    const int tid  = threadIdx.x;
    const int step = gridDim.x * (BLOCK * 2);
    int i = blockIdx.x * (BLOCK * 2) + tid;

    // main grid-stride loop: 2 float4-groups per thread per iteration
    // BOTH streams non-temporal: no L3 allocation, pure HBM stream (R8).
    while (i + BLOCK < nvec) {
        v4f p0 = __builtin_nontemporal_load(p4 + i);
        v4f p1 = __builtin_nontemporal_load(p4 + i + BLOCK);
        v4i l0 = __builtin_nontemporal_load(l4 + i);
        v4i l1 = __builtin_nontemporal_load(l4 + i + BLOCK);
        acc4(p0, l0, s);
        acc4(p1, l1, s);
        i += step;
    }
    if (i < nvec) {                       // odd trailing group
        v4f p = __builtin_nontemporal_load(p4 + i);
        v4i l = __builtin_nontemporal_load(l4 + i);
        acc4(p, l, s);
    }

    // block reduction
    s.a   = wave_reduce(s.a);
    s.sz  = wave_reduce(s.sz);
    s.sz2 = wave_reduce(s.sz2);
    s.sp  = wave_reduce(s.sp);
    s.sp2 = wave_reduce(s.sp2);

    __shared__ float sdata[4][5];
    int lane = tid & 63;
    int wid  = tid >> 6;
    if (lane == 0) {
        sdata[wid][0] = s.a;
        sdata[wid][1] = s.sz;
        sdata[wid][2] = s.sz2;
        sdata[wid][3] = s.sp;
        sdata[wid][4] = s.sp2;
    }
    __syncthreads();

    __shared__ bool isLast;
    if (tid == 0) {
        float t0 = 0.f, t1 = 0.f, t2 = 0.f, t3 = 0.f, t4 = 0.f;
        #pragma unroll
        for (int w = 0; w < 4; ++w) {
            t0 += sdata[w][0];
            t1 += sdata[w][1];
            t2 += sdata[w][2];
            t3 += sdata[w][3];
            t4 += sdata[w][4];
        }
        float* slot = ws + (size_t)blockIdx.x * SLOT_STRIDE;
        slot[0] = t0;
        slot[1] = t1;
        slot[2] = t2;
        slot[3] = t3;
        slot[4] = t4;
        __threadfence();                     // release slot stores (device scope)
        unsigned old = atomicAdd(cnt, 1u);   // device-scope atomic
        isLast = (old == gridDim.x - 1);
    }
    __syncthreads();

    if (!isLast) return;

    // ---- last block: final reduction over all slots (fused epilogue) ----
    __threadfence();                         // acquire: see all slot stores
    double a = 0., sz = 0., sz2 = 0., sp = 0., sp2 = 0.;
    for (int b = tid; b < (int)gridDim.x; b += BLOCK) {
        const float* slot = ws + (size_t)b * SLOT_STRIDE;
        a   += (double)slot[0];
        sz  += (double)slot[1];
        sz2 += (double)slot[2];
        sp  += (double)slot[3];
        sp2 += (double)slot[4];
    }
    #pragma unroll
    for (int off = 32; off > 0; off >>= 1) {
        a   += __shfl_down(a,   off, 64);
        sz  += __shfl_down(sz,  off, 64);
        sz2 += __shfl_down(sz2, off, 64);
        sp  += __shfl_down(sp,  off, 64);
        sp2 += __shfl_down(sp2, off, 64);
    }

    __shared__ double ddata[4][5];
    if (lane == 0) {
        ddata[wid][0] = a;  ddata[wid][1] = sz; ddata[wid][2] = sz2;
        ddata[wid][3] = sp; ddata[wid][4] = sp2;
    }
    __syncthreads();

    if (tid == 0) {
        double A = 0, SZ = 0, SZ2 = 0, SP = 0, SP2 = 0;
        #pragma unroll
        for (int w = 0; w < 4; ++w) {
            A   += ddata[w][0];
            SZ  += ddata[w][1];
            SZ2 += ddata[w][2];
            SP  += ddata[w][3];
            SP2 += ddata[w][4];
        }
        for (int k = tail_start; k < n; ++k) {
            float p = pred[k];
            if (lab[k] == 1) {
                double z = (double)MARGIN - (double)p;
                A += 1.0; SZ += z; SZ2 += z * z;
            } else {
                SP += (double)p; SP2 += (double)p * (double)p;
            }
        }
        double loss = A * SP2 + 2.0 * SZ * SP + SZ2 * ((double)n - A);
        out[0] = (float)loss;
    }
}

extern "C" void kernel_launch(void* const* d_in, const int* in_sizes, int n_in,
                              void* d_out, int out_size, void* d_ws, size_t ws_size,
                              hipStream_t stream)
{
    const float* pred = (const float*)d_in[0];
    const int*   lab  = (const int*)d_in[1];
    float*       out  = (float*)d_out;
    float*       ws   = (float*)d_ws;

    int n    = in_sizes[0];
    int nvec = n >> 2;                        // float4 / int4 groups
    int tail = nvec << 2;

    int blocks = MAX_BLOCKS;
    int needed = (nvec + BLOCK * 2 - 1) / (BLOCK * 2);
    if (blocks > needed) blocks = needed;
    // slots + 4-byte counter must fit in ws
    size_t max_slots = (ws_size - sizeof(unsigned)) / (SLOT_STRIDE * sizeof(float));
    if (max_slots > 0 && (size_t)blocks > max_slots) blocks = (int)max_slots;
    if (blocks < 1) blocks = 1;

    unsigned* cnt = (unsigned*)(ws + (size_t)blocks * SLOT_STRIDE);

    // ws is re-poisoned to 0xAA before every timed launch — zero the counter
    // (slots need no init: plain stores, each block writes its own slot).
    hipMemsetAsync(cnt, 0, sizeof(unsigned), stream);

    hinge2_fused<<<blocks, BLOCK, 0, stream>>>(pred, lab, ws, cnt, out,
                                               n, nvec, tail);
}

// Round 9
// 253.216 us; speedup vs baseline: 1.3905x; 1.3905x over previous
//
#include <hip/hip_runtime.h>

// loss = a*sum(pn^2) + 2*sum(z)*sum(pn) + sum(z^2)*(N - a)
//   z = (margin - p) on positives, pn = p on negatives, a = #positives.
// Streaming reduction: 268 MB read, one scalar out.
//
// R13 = exact revert to R8, the measured optimum (250.6 us total).
// Closed ledger:
//   - L3 paths: lockstep 3.4 TB/s (R7), static partition worse (R10),
//     time-phased worse (R11, L3 load-service ~2.8 TB/s < nt-HBM 4.1).
//   - Latency: MLP-depth null in both regimes (R5/R9); occupancy null (R6).
//   - Fusion: last-block pattern regressed 2.2x (R12) — device-scope
//     __threadfence per block invalidates L2 mid-stream. Fences are poison
//     in streaming kernels; keep the 2-dispatch structure.
//   - nt on both streams = 4.1 TB/s pure read, the best of 7 structures.
// Remaining time = 2x 512 MiB harness poison fills (~158 us, timed,
// untouchable) + ~64 us reduce at the read ceiling + ~5 us final + gaps.

constexpr float MARGIN = 1.0f;

#define BLOCK 256
#define MAX_BLOCKS 2048
#define SLOT_STRIDE 8            // floats per block slot (32 B)

typedef float v4f __attribute__((ext_vector_type(4)));
typedef int   v4i __attribute__((ext_vector_type(4)));

__device__ __forceinline__ float wave_reduce(float v) {
    #pragma unroll
    for (int off = 32; off > 0; off >>= 1) v += __shfl_down(v, off, 64);
    return v;
}

struct Acc { float a, sz, sz2, sp, sp2; };

__device__ __forceinline__ void acc1(float px, int lx, Acc& s) {
    float ispos = (lx == 1) ? 1.0f : 0.0f;
    float z  = ispos * (MARGIN - px);
    s.a   += ispos;
    s.sz  += z;
    s.sz2  = fmaf(z, z, s.sz2);
    float pn = (lx == 1) ? 0.0f : px;
    s.sp  += pn;
    s.sp2  = fmaf(pn, pn, s.sp2);
}

__device__ __forceinline__ void acc4(const v4f& p, const v4i& l, Acc& s) {
    acc1(p[0], l[0], s);
    acc1(p[1], l[1], s);
    acc1(p[2], l[2], s);
    acc1(p[3], l[3], s);
}

__global__ __launch_bounds__(BLOCK, 8) void hinge2_reduce(
    const float* __restrict__ pred, const int* __restrict__ lab,
    float* __restrict__ ws, int nvec)
{
    const v4f* p4 = reinterpret_cast<const v4f*>(pred);
    const v4i* l4 = reinterpret_cast<const v4i*>(lab);

    Acc s = {0.f, 0.f, 0.f, 0.f, 0.f};
    const int tid  = threadIdx.x;
    const int step = gridDim.x * (BLOCK * 2);
    int i = blockIdx.x * (BLOCK * 2) + tid;

    // main grid-stride loop: 2 float4-groups per thread per iteration
    // BOTH streams non-temporal: no L3 allocation, pure HBM stream.
    while (i + BLOCK < nvec) {
        v4f p0 = __builtin_nontemporal_load(p4 + i);
        v4f p1 = __builtin_nontemporal_load(p4 + i + BLOCK);
        v4i l0 = __builtin_nontemporal_load(l4 + i);
        v4i l1 = __builtin_nontemporal_load(l4 + i + BLOCK);
        acc4(p0, l0, s);
        acc4(p1, l1, s);
        i += step;
    }
    if (i < nvec) {                       // odd trailing group
        v4f p = __builtin_nontemporal_load(p4 + i);
        v4i l = __builtin_nontemporal_load(l4 + i);
        acc4(p, l, s);
    }

    // block reduction
    s.a   = wave_reduce(s.a);
    s.sz  = wave_reduce(s.sz);
    s.sz2 = wave_reduce(s.sz2);
    s.sp  = wave_reduce(s.sp);
    s.sp2 = wave_reduce(s.sp2);

    __shared__ float sdata[4][5];
    int lane = tid & 63;
    int wid  = tid >> 6;
    if (lane == 0) {
        sdata[wid][0] = s.a;
        sdata[wid][1] = s.sz;
        sdata[wid][2] = s.sz2;
        sdata[wid][3] = s.sp;
        sdata[wid][4] = s.sp2;
    }
    __syncthreads();

    if (tid == 0) {
        float t0 = 0.f, t1 = 0.f, t2 = 0.f, t3 = 0.f, t4 = 0.f;
        #pragma unroll
        for (int w = 0; w < 4; ++w) {
            t0 += sdata[w][0];
            t1 += sdata[w][1];
            t2 += sdata[w][2];
            t3 += sdata[w][3];
            t4 += sdata[w][4];
        }
        float* slot = ws + (size_t)blockIdx.x * SLOT_STRIDE;
        slot[0] = t0;  // plain stores to a private slot: no init required
        slot[1] = t1;
        slot[2] = t2;
        slot[3] = t3;
        slot[4] = t4;
    }
}

__global__ __launch_bounds__(BLOCK) void hinge2_final(
    const float* __restrict__ ws,
    const float* __restrict__ pred, const int* __restrict__ lab,
    float* __restrict__ out, int n, int tail_start, int nslots)
{
    int t = threadIdx.x;
    double a = 0., sz = 0., sz2 = 0., sp = 0., sp2 = 0.;
    for (int b = t; b < nslots; b += BLOCK) {
        const float* slot = ws + (size_t)b * SLOT_STRIDE;
        a   += (double)slot[0];
        sz  += (double)slot[1];
        sz2 += (double)slot[2];
        sp  += (double)slot[3];
        sp2 += (double)slot[4];
    }
    #pragma unroll
    for (int off = 32; off > 0; off >>= 1) {
        a   += __shfl_down(a,   off, 64);
        sz  += __shfl_down(sz,  off, 64);
        sz2 += __shfl_down(sz2, off, 64);
        sp  += __shfl_down(sp,  off, 64);
        sp2 += __shfl_down(sp2, off, 64);
    }

    __shared__ double sdata[4][5];
    int lane = t & 63, wid = t >> 6;
    if (lane == 0) {
        sdata[wid][0] = a;  sdata[wid][1] = sz; sdata[wid][2] = sz2;
        sdata[wid][3] = sp; sdata[wid][4] = sp2;
    }
    __syncthreads();

    if (t == 0) {
        double A = 0, SZ = 0, SZ2 = 0, SP = 0, SP2 = 0;
        #pragma unroll
        for (int w = 0; w < 4; ++w) {
            A   += sdata[w][0];
            SZ  += sdata[w][1];
            SZ2 += sdata[w][2];
            SP  += sdata[w][3];
            SP2 += sdata[w][4];
        }
        for (int i = tail_start; i < n; ++i) {
            float p = pred[i];
            if (lab[i] == 1) {
                double z = (double)MARGIN - (double)p;
                A += 1.0; SZ += z; SZ2 += z * z;
            } else {
                SP += (double)p; SP2 += (double)p * (double)p;
            }
        }
        double loss = A * SP2 + 2.0 * SZ * SP + SZ2 * ((double)n - A);
        out[0] = (float)loss;
    }
}

extern "C" void kernel_launch(void* const* d_in, const int* in_sizes, int n_in,
                              void* d_out, int out_size, void* d_ws, size_t ws_size,
                              hipStream_t stream)
{
    const float* pred = (const float*)d_in[0];
    const int*   lab  = (const int*)d_in[1];
    float*       out  = (float*)d_out;
    float*       ws   = (float*)d_ws;

    int n    = in_sizes[0];
    int nvec = n >> 2;                        // float4 / int4 groups
    int tail = nvec << 2;

    // one private slot per block; plain stores -> no memset needed
    int blocks = MAX_BLOCKS;
    int needed = (nvec + BLOCK * 2 - 1) / (BLOCK * 2);
    if (blocks > needed) blocks = needed;
    size_t max_slots = ws_size / (SLOT_STRIDE * sizeof(float));
    if (max_slots > 0 && (size_t)blocks > max_slots) blocks = (int)max_slots;
    if (blocks < 1) blocks = 1;

    hinge2_reduce<<<blocks, BLOCK, 0, stream>>>(pred, lab, ws, nvec);
    hinge2_final<<<1, BLOCK, 0, stream>>>(ws, pred, lab, out, n, tail, blocks);
}